// Round 8
// baseline (145.222 us; speedup 1.0000x reference)
//
#include <hip/hip_runtime.h>

// Problem constants (fixed by the reference module)
#define B_ 16
#define L_ 2048
#define D_ 128
#define GROUP_ 16
#define NG_ (L_ / GROUP_)   // 128
#define LOG2E_ 1.44269504088896340736f

// DPP-based butterfly add within each 16-lane row (full-rate VALU, no LDS).
template<int CTRL>
__device__ __forceinline__ float dpp_add(float v) {
    int x = __builtin_amdgcn_update_dpp(0, __float_as_int(v), CTRL, 0xF, 0xF, false);
    return v + __int_as_float(x);
}
__device__ __forceinline__ float row16_sum(float v) {
    v = dpp_add<0xB1>(v);   // quad_perm(1,0,3,2)  ~ xor 1
    v = dpp_add<0x4E>(v);   // quad_perm(2,3,0,1)  ~ xor 2
    v = dpp_add<0x141>(v);  // row_half_mirror     ~ xor 4
    v = dpp_add<0x140>(v);  // row_mirror          ~ xor 8
    return v;
}

// One block per (b,g) group. 256 threads = 16 rows x 16 lanes, 8 elems/thread.
//
// R2-R7 law: dur ~= VALU_busy_time + 13.5us in every variant; busy was
// MINIMAL in the leanest body (R2, ~39us) and every "clever" addition
// (batched rcp, precompute, SIMD rotation) only raised busy. Fit gives
// trans ~16 issue-cyc wave64 => 4 trans/elem-step is the dominant floor.
// This round: leanest possible body (exp2-folded sigmoid, NO clamps --
// without a batch product, exp2->inf is safe: rcp(inf)=0 hits the exact
// tanh=+-1 limit), flag handoff (1 barrier total), and
// __launch_bounds__(256,8) to request full 8-block/CU residency so
// other blocks' issue covers each block's serial handoff chain + tail.
__global__ __launch_bounds__(256, 8) void ncn_kernel(
    const float* __restrict__ x,       // (B, L, D)
    const int*   __restrict__ gt,      // (B, L) permutation
    const int*   __restrict__ ctxlens, // (B,)
    const float* __restrict__ W,       // (2D,)
    const float* __restrict__ nalpha,  // (2,)
    const float* __restrict__ ngamma,  // (2D,)
    const float* __restrict__ nbeta,   // (2D,)
    float* __restrict__ out)           // (2, B, L, D) concat: yi_out, ya_out
{
    const int blk = blockIdx.x;
    const int b   = blk >> 7;      // / NG_
    const int g   = blk & (NG_ - 1);
    const int tid = threadIdx.x;
    const int row = tid >> 4;      // 0..15 (token within group)
    const int rl  = tid & 15;      // 0..15 (lane within row)
    const int d0  = rl << 3;       // 8 d-elements per thread

    __shared__ float s_xj[GROUP_][D_];   // one slot per step: no WAR hazard
    __shared__ int   s_flag[GROUP_];     // publish flags

    if (tid < GROUP_) s_flag[tid] = 0;

    const float a1 = nalpha[0];
    const float a2 = nalpha[1];
    const float ca = -a1 * LOG2E_;        // u = ca*(xi + sim*xj) = -a1*log2e*2T
    const float S  = -2.0f * a2 * LOG2E_; // za = S*xa, so exp2(za) direct
    const bool  selMin = (S < 0.0f);      // leaky-relu under sign flip

    // Per-chunk constants in registers (reused 16x). Folded/pre-scaled forms.
    float Wi[8], Wj[8], G1S[8], B1S[8], G2[8], B2[8];
    {
        float g1r[8], b1r[8], g2r[8], b2r[8];
        *(float4*)&Wi[0]  = *(const float4*)(W + d0);
        *(float4*)&Wi[4]  = *(const float4*)(W + d0 + 4);
        *(float4*)&Wj[0]  = *(const float4*)(W + D_ + d0);
        *(float4*)&Wj[4]  = *(const float4*)(W + D_ + d0 + 4);
        *(float4*)&g1r[0] = *(const float4*)(ngamma + d0);
        *(float4*)&g1r[4] = *(const float4*)(ngamma + d0 + 4);
        *(float4*)&g2r[0] = *(const float4*)(ngamma + D_ + d0);
        *(float4*)&g2r[4] = *(const float4*)(ngamma + D_ + d0 + 4);
        *(float4*)&b1r[0] = *(const float4*)(nbeta + d0);
        *(float4*)&b1r[4] = *(const float4*)(nbeta + d0 + 4);
        *(float4*)&b2r[0] = *(const float4*)(nbeta + D_ + d0);
        *(float4*)&b2r[4] = *(const float4*)(nbeta + D_ + d0 + 4);
#pragma unroll
        for (int k = 0; k < 8; ++k) {
            G1S[k] = S * 2.0f * g1r[k];          // S*(2*g1)
            B1S[k] = S * (b1r[k] - g1r[k]);      // S*(b1-g1)
            G2[k]  = 2.0f * g2r[k];
            B2[k]  = b2r[k] - g2r[k];
        }
    }

    // Gather this row's token
    const int l   = g * GROUP_ + row;
    const int tok = gt[b * L_ + l];
    const float* xp = x + ((size_t)(b * L_ + tok)) * D_ + d0;

    float xi[8], za[8];
    *(float4*)&xi[0] = *(const float4*)xp;
    *(float4*)&xi[4] = *(const float4*)(xp + 4);
#pragma unroll
    for (int k = 0; k < 8; ++k) za[k] = 0.0f;

    __syncthreads();   // flags zeroed & visible (only block-wide barrier)

    volatile int* vflag = (volatile int*)s_flag;

    // Row 0 publishes slot 0 (its loaded xi)
    if (row == 0) {
        *(float4*)&s_xj[0][d0]     = *(float4*)&xi[0];
        *(float4*)&s_xj[0][d0 + 4] = *(float4*)&xi[4];
        __threadfence_block();          // data before flag
        if (rl == 0) vflag[0] = 1;
    }

    for (int j = 0; j < GROUP_; ++j) {
        // Wait until slot j is published (steady state: falls through).
        while (vflag[j] == 0) { }
        __threadfence_block();          // acquire

        float xjv[8];
        *(float4*)&xjv[0] = *(const float4*)&s_xj[j][d0];
        *(float4*)&xjv[4] = *(const float4*)&s_xj[j][d0 + 4];

        // sim = dot(xi,Wi) + dot(xj,Wj): combined, one 16-lane DPP reduce.
        float s = 0.0f, s2 = 0.0f;
#pragma unroll
        for (int k = 0; k < 8; ++k) s  = fmaf(xi[k], Wi[k], s);
#pragma unroll
        for (int k = 0; k < 8; ++k) s2 = fmaf(xjv[k], Wj[k], s2);
        const float sim = row16_sum(s + s2);

#pragma unroll
        for (int k = 0; k < 8; ++k) {
            // u = -2*a1*log2e * T,  T = 0.5*(xi + sim*xj)
            float T2  = fmaf(sim, xjv[k], xi[k]);
            float e1  = __builtin_amdgcn_exp2f(ca * T2);
            float r1  = __builtin_amdgcn_rcpf(1.0f + e1);   // inf-safe: rcp(inf)=0
            float tnS = fmaf(G1S[k], r1, B1S[k]);           // S*(g1*tanh+b1)
            float alt = 0.01f * tnS;
            float FvS = selMin ? fminf(tnS, alt) : fmaxf(tnS, alt);
            za[k] += FvS;                                   // za = S * xa
            float e2  = __builtin_amdgcn_exp2f(za[k]);
            float r2  = __builtin_amdgcn_rcpf(1.0f + e2);
            xi[k] += fmaf(G2[k], r2, B2[k]);                // xi += g2*tanh(a2*xa)+b2
        }

        // Publisher of step j+1 releases its slot as soon as it's ready.
        if (j < GROUP_ - 1 && row == j + 1) {
            *(float4*)&s_xj[j + 1][d0]     = *(float4*)&xi[0];
            *(float4*)&s_xj[j + 1][d0 + 4] = *(float4*)&xi[4];
            __threadfence_block();      // data before flag
            if (rl == 0) vflag[j + 1] = 1;
        }
    }

    // Recover xa = za / S
    const float invS = 1.0f / S;
    float xa[8];
#pragma unroll
    for (int k = 0; k < 8; ++k) xa[k] = za[k] * invS;

    const bool valid = (g * GROUP_) < ctxlens[b];
    if (!valid) {
#pragma unroll
        for (int k = 0; k < 8; ++k) { xi[k] = 0.0f; xa[k] = 0.0f; }
    }

    // Scatter back through the permutation (bijective -> every out elem written)
    float* o1 = out + ((size_t)(b * L_ + tok)) * D_ + d0;
    float* o2 = o1 + (size_t)B_ * L_ * D_;
    *(float4*)o1       = *(float4*)&xi[0];
    *(float4*)(o1 + 4) = *(float4*)&xi[4];
    *(float4*)o2       = *(float4*)&xa[0];
    *(float4*)(o2 + 4) = *(float4*)&xa[4];
}

extern "C" void kernel_launch(void* const* d_in, const int* in_sizes, int n_in,
                              void* d_out, int out_size, void* d_ws, size_t ws_size,
                              hipStream_t stream) {
    const float* x  = (const float*)d_in[0];
    const int*   gt = (const int*)d_in[1];
    const int*   cl = (const int*)d_in[2];
    const float* W  = (const float*)d_in[3];
    const float* na = (const float*)d_in[4];
    const float* ng = (const float*)d_in[5];
    const float* nb = (const float*)d_in[6];
    float* out = (float*)d_out;

    ncn_kernel<<<B_ * NG_, 256, 0, stream>>>(x, gt, cl, W, na, ng, nb, out);
}

// Round 9
// 119.270 us; speedup vs baseline: 1.2176x; 1.2176x over previous
//
#include <hip/hip_runtime.h>

// Problem constants (fixed by the reference module)
#define B_ 16
#define L_ 2048
#define D_ 128
#define GROUP_ 16
#define NG_ (L_ / GROUP_)   // 128
#define LOG2E_ 1.44269504088896340736f

// DPP-based butterfly add within each 16-lane row (full-rate VALU, no LDS).
template<int CTRL>
__device__ __forceinline__ float dpp_add(float v) {
    int x = __builtin_amdgcn_update_dpp(0, __float_as_int(v), CTRL, 0xF, 0xF, false);
    return v + __int_as_float(x);
}
__device__ __forceinline__ float row16_sum(float v) {
    v = dpp_add<0xB1>(v);   // quad_perm(1,0,3,2)  ~ xor 1
    v = dpp_add<0x4E>(v);   // quad_perm(2,3,0,1)  ~ xor 2
    v = dpp_add<0x141>(v);  // row_half_mirror     ~ xor 4
    v = dpp_add<0x140>(v);  // row_mirror          ~ xor 8
    return v;
}

// One block per (b,g) group. 256 threads = 16 rows x 16 lanes, 8 elems/thread.
//
// R1-R8 ledger: all non-spilling variants plateau at 53.5-54.5us regardless
// of barrier count (2/1/0), trans count (32/18), handoff mechanism, SIMD
// mapping. R8 proved (256,8) forces VGPR=32 -> scratch spills (FETCH 8->115MB).
// This round: the one unmeasured cell — leanest body (4 trans/elem, no
// clamps: exp2->inf is safe since rcp(inf)=0 = exact tanh limit) at the
// known-good (256,4) bounds with the best-measured handoff (double-buffered
// LDS slot + single barrier per step).
__global__ __launch_bounds__(256, 4) void ncn_kernel(
    const float* __restrict__ x,       // (B, L, D)
    const int*   __restrict__ gt,      // (B, L) permutation
    const int*   __restrict__ ctxlens, // (B,)
    const float* __restrict__ W,       // (2D,)
    const float* __restrict__ nalpha,  // (2,)
    const float* __restrict__ ngamma,  // (2D,)
    const float* __restrict__ nbeta,   // (2D,)
    float* __restrict__ out)           // (2, B, L, D) concat: yi_out, ya_out
{
    const int blk = blockIdx.x;
    const int b   = blk >> 7;      // / NG_
    const int g   = blk & (NG_ - 1);
    const int tid = threadIdx.x;
    const int row = tid >> 4;      // 0..15 (token within group)
    const int rl  = tid & 15;      // 0..15 (lane within row)
    const int d0  = rl << 3;       // 8 d-elements per thread

    __shared__ float s_xj[2][D_];  // double-buffered broadcast row

    const float a1 = nalpha[0];
    const float a2 = nalpha[1];
    const float ca = -a1 * LOG2E_;        // u = ca*(xi + sim*xj) = -2*a1*log2e*T
    const float S  = -2.0f * a2 * LOG2E_; // za = S*xa, so exp2(za) direct
    const bool  selMin = (S < 0.0f);      // leaky-relu under sign flip

    // Per-chunk constants in registers (reused 16x). Folded/pre-scaled forms.
    float Wi[8], Wj[8], G1S[8], B1S[8], G2[8], B2[8];
    {
        float g1r[8], b1r[8], g2r[8], b2r[8];
        *(float4*)&Wi[0]  = *(const float4*)(W + d0);
        *(float4*)&Wi[4]  = *(const float4*)(W + d0 + 4);
        *(float4*)&Wj[0]  = *(const float4*)(W + D_ + d0);
        *(float4*)&Wj[4]  = *(const float4*)(W + D_ + d0 + 4);
        *(float4*)&g1r[0] = *(const float4*)(ngamma + d0);
        *(float4*)&g1r[4] = *(const float4*)(ngamma + d0 + 4);
        *(float4*)&g2r[0] = *(const float4*)(ngamma + D_ + d0);
        *(float4*)&g2r[4] = *(const float4*)(ngamma + D_ + d0 + 4);
        *(float4*)&b1r[0] = *(const float4*)(nbeta + d0);
        *(float4*)&b1r[4] = *(const float4*)(nbeta + d0 + 4);
        *(float4*)&b2r[0] = *(const float4*)(nbeta + D_ + d0);
        *(float4*)&b2r[4] = *(const float4*)(nbeta + D_ + d0 + 4);
#pragma unroll
        for (int k = 0; k < 8; ++k) {
            G1S[k] = S * 2.0f * g1r[k];          // S*(2*g1)
            B1S[k] = S * (b1r[k] - g1r[k]);      // S*(b1-g1)
            G2[k]  = 2.0f * g2r[k];
            B2[k]  = b2r[k] - g2r[k];
        }
    }

    // Gather this row's token
    const int l   = g * GROUP_ + row;
    const int tok = gt[b * L_ + l];
    const float* xp = x + ((size_t)(b * L_ + tok)) * D_ + d0;

    float xi[8], za[8];
    *(float4*)&xi[0] = *(const float4*)xp;
    *(float4*)&xi[4] = *(const float4*)(xp + 4);
#pragma unroll
    for (int k = 0; k < 8; ++k) za[k] = 0.0f;

    // Row 0 publishes its initial xi into buffer 0
    if (row == 0) {
        *(float4*)&s_xj[0][d0]     = *(float4*)&xi[0];
        *(float4*)&s_xj[0][d0 + 4] = *(float4*)&xi[4];
    }
    __syncthreads();

    for (int j = 0; j < GROUP_; ++j) {
        const int p = j & 1;

        float xjv[8];
        *(float4*)&xjv[0] = *(const float4*)&s_xj[p][d0];
        *(float4*)&xjv[4] = *(const float4*)&s_xj[p][d0 + 4];

        // sim = dot(xi,Wi) + dot(xj,Wj): combined, one 16-lane DPP reduce.
        float s = 0.0f, s2 = 0.0f;
#pragma unroll
        for (int k = 0; k < 8; ++k) s  = fmaf(xi[k], Wi[k], s);
#pragma unroll
        for (int k = 0; k < 8; ++k) s2 = fmaf(xjv[k], Wj[k], s2);
        const float sim = row16_sum(s + s2);

#pragma unroll
        for (int k = 0; k < 8; ++k) {
            // u = -2*a1*log2e * T,  T = 0.5*(xi + sim*xj)
            float T2  = fmaf(sim, xjv[k], xi[k]);
            float e1  = __builtin_amdgcn_exp2f(ca * T2);
            float r1  = __builtin_amdgcn_rcpf(1.0f + e1);   // inf-safe: rcp(inf)=0
            float tnS = fmaf(G1S[k], r1, B1S[k]);           // S*(g1*tanh+b1)
            float alt = 0.01f * tnS;
            float FvS = selMin ? fminf(tnS, alt) : fmaxf(tnS, alt);
            za[k] += FvS;                                   // za = S * xa
            float e2  = __builtin_amdgcn_exp2f(za[k]);
            float r2  = __builtin_amdgcn_rcpf(1.0f + e2);
            xi[k] += fmaf(G2[k], r2, B2[k]);                // xi += g2*tanh(a2*xa)+b2
        }

        // Next step's broadcaster writes the OTHER buffer; the single
        // barrier orders both visibility and WAR reuse.
        if (j + 1 < GROUP_ && row == j + 1) {
            *(float4*)&s_xj[p ^ 1][d0]     = *(float4*)&xi[0];
            *(float4*)&s_xj[p ^ 1][d0 + 4] = *(float4*)&xi[4];
        }
        __syncthreads();
    }

    // Recover xa = za / S
    const float invS = 1.0f / S;
    float xa[8];
#pragma unroll
    for (int k = 0; k < 8; ++k) xa[k] = za[k] * invS;

    const bool valid = (g * GROUP_) < ctxlens[b];
    if (!valid) {
#pragma unroll
        for (int k = 0; k < 8; ++k) { xi[k] = 0.0f; xa[k] = 0.0f; }
    }

    // Scatter back through the permutation (bijective -> every out elem written)
    float* o1 = out + ((size_t)(b * L_ + tok)) * D_ + d0;
    float* o2 = o1 + (size_t)B_ * L_ * D_;
    *(float4*)o1       = *(float4*)&xi[0];
    *(float4*)(o1 + 4) = *(float4*)&xi[4];
    *(float4*)o2       = *(float4*)&xa[0];
    *(float4*)(o2 + 4) = *(float4*)&xa[4];
}

extern "C" void kernel_launch(void* const* d_in, const int* in_sizes, int n_in,
                              void* d_out, int out_size, void* d_ws, size_t ws_size,
                              hipStream_t stream) {
    const float* x  = (const float*)d_in[0];
    const int*   gt = (const int*)d_in[1];
    const int*   cl = (const int*)d_in[2];
    const float* W  = (const float*)d_in[3];
    const float* na = (const float*)d_in[4];
    const float* ng = (const float*)d_in[5];
    const float* nb = (const float*)d_in[6];
    float* out = (float*)d_out;

    ncn_kernel<<<B_ * NG_, 256, 0, stream>>>(x, gt, cl, W, na, ng, nb, out);
}

// Round 10
// 117.223 us; speedup vs baseline: 1.2389x; 1.0175x over previous
//
#include <hip/hip_runtime.h>

// Problem constants (fixed by the reference module)
#define B_ 16
#define L_ 2048
#define D_ 128
#define GROUP_ 16
#define NG_ (L_ / GROUP_)   // 128
#define LOG2E_ 1.44269504088896340736f

typedef float v2 __attribute__((ext_vector_type(2)));

// DPP-based butterfly add within each 16-lane row (full-rate VALU, no LDS).
template<int CTRL>
__device__ __forceinline__ float dpp_add(float v) {
    int x = __builtin_amdgcn_update_dpp(0, __float_as_int(v), CTRL, 0xF, 0xF, false);
    return v + __int_as_float(x);
}
__device__ __forceinline__ float row16_sum(float v) {
    v = dpp_add<0xB1>(v);   // quad_perm(1,0,3,2)  ~ xor 1
    v = dpp_add<0x4E>(v);   // quad_perm(2,3,0,1)  ~ xor 2
    v = dpp_add<0x141>(v);  // row_half_mirror     ~ xor 4
    v = dpp_add<0x140>(v);  // row_mirror          ~ xor 8
    return v;
}

// One block per (b,g) group. 256 threads = 16 rows x 16 lanes, 8 elems/thread.
//
// R9 result: leanest body + (256,4) = 48us (busy ~34us + ~14us gap law).
// Issue audit: ~200 cyc/wave-step non-trans VALU + ~500 trans. This round:
// pack ALL non-trans elementwise/dot math into float2 -> v_pk_fma_f32 /
// v_pk_add_f32 / v_pk_mul_f32 (VOP3P, 2 fp32 per issue slot). Trans
// (v_exp/v_rcp) stays scalar. Numerics bitwise identical to R9.
__global__ __launch_bounds__(256, 4) void ncn_kernel(
    const float* __restrict__ x,       // (B, L, D)
    const int*   __restrict__ gt,      // (B, L) permutation
    const int*   __restrict__ ctxlens, // (B,)
    const float* __restrict__ W,       // (2D,)
    const float* __restrict__ nalpha,  // (2,)
    const float* __restrict__ ngamma,  // (2D,)
    const float* __restrict__ nbeta,   // (2D,)
    float* __restrict__ out)           // (2, B, L, D) concat: yi_out, ya_out
{
    const int blk = blockIdx.x;
    const int b   = blk >> 7;      // / NG_
    const int g   = blk & (NG_ - 1);
    const int tid = threadIdx.x;
    const int row = tid >> 4;      // 0..15 (token within group)
    const int rl  = tid & 15;      // 0..15 (lane within row)
    const int d0  = rl << 3;       // 8 d-elements per thread

    __shared__ float s_xj[2][D_];  // double-buffered broadcast row

    const float a1 = nalpha[0];
    const float a2 = nalpha[1];
    const float ca = -a1 * LOG2E_;        // u = ca*(xi + sim*xj) = -2*a1*log2e*T
    const float S  = -2.0f * a2 * LOG2E_; // za = S*xa, so exp2(za) direct
    const bool  selMin = (S < 0.0f);      // leaky-relu under sign flip

    // Per-chunk constants in registers (reused 16x), as packed v2 pairs.
    v2 Wi[4], Wj[4], G1S[4], B1S[4], G2[4], B2[4];
    {
        float4 wA = *(const float4*)(W + d0);
        float4 wB = *(const float4*)(W + d0 + 4);
        float4 vA = *(const float4*)(W + D_ + d0);
        float4 vB = *(const float4*)(W + D_ + d0 + 4);
        Wi[0] = (v2){wA.x, wA.y}; Wi[1] = (v2){wA.z, wA.w};
        Wi[2] = (v2){wB.x, wB.y}; Wi[3] = (v2){wB.z, wB.w};
        Wj[0] = (v2){vA.x, vA.y}; Wj[1] = (v2){vA.z, vA.w};
        Wj[2] = (v2){vB.x, vB.y}; Wj[3] = (v2){vB.z, vB.w};

        float4 g1A = *(const float4*)(ngamma + d0);
        float4 g1B = *(const float4*)(ngamma + d0 + 4);
        float4 g2A = *(const float4*)(ngamma + D_ + d0);
        float4 g2B = *(const float4*)(ngamma + D_ + d0 + 4);
        float4 b1A = *(const float4*)(nbeta + d0);
        float4 b1B = *(const float4*)(nbeta + d0 + 4);
        float4 b2A = *(const float4*)(nbeta + D_ + d0);
        float4 b2B = *(const float4*)(nbeta + D_ + d0 + 4);

        v2 g1v[4] = {(v2){g1A.x,g1A.y},(v2){g1A.z,g1A.w},(v2){g1B.x,g1B.y},(v2){g1B.z,g1B.w}};
        v2 b1v[4] = {(v2){b1A.x,b1A.y},(v2){b1A.z,b1A.w},(v2){b1B.x,b1B.y},(v2){b1B.z,b1B.w}};
        v2 g2v[4] = {(v2){g2A.x,g2A.y},(v2){g2A.z,g2A.w},(v2){g2B.x,g2B.y},(v2){g2B.z,g2B.w}};
        v2 b2v[4] = {(v2){b2A.x,b2A.y},(v2){b2A.z,b2A.w},(v2){b2B.x,b2B.y},(v2){b2B.z,b2B.w}};
#pragma unroll
        for (int k = 0; k < 4; ++k) {
            G1S[k] = (S * 2.0f) * g1v[k];        // S*(2*g1)
            B1S[k] = S * (b1v[k] - g1v[k]);      // S*(b1-g1)
            G2[k]  = 2.0f * g2v[k];
            B2[k]  = b2v[k] - g2v[k];
        }
    }

    // Gather this row's token
    const int l   = g * GROUP_ + row;
    const int tok = gt[b * L_ + l];
    const float* xp = x + ((size_t)(b * L_ + tok)) * D_ + d0;

    v2 xi[4], za[4];
    {
        float4 xA = *(const float4*)xp;
        float4 xB = *(const float4*)(xp + 4);
        xi[0] = (v2){xA.x, xA.y}; xi[1] = (v2){xA.z, xA.w};
        xi[2] = (v2){xB.x, xB.y}; xi[3] = (v2){xB.z, xB.w};
    }
#pragma unroll
    for (int k = 0; k < 4; ++k) za[k] = (v2){0.0f, 0.0f};

    // Row 0 publishes its initial xi into buffer 0
    if (row == 0) {
        *(v2*)&s_xj[0][d0]     = xi[0];
        *(v2*)&s_xj[0][d0 + 2] = xi[1];
        *(v2*)&s_xj[0][d0 + 4] = xi[2];
        *(v2*)&s_xj[0][d0 + 6] = xi[3];
    }
    __syncthreads();

    for (int j = 0; j < GROUP_; ++j) {
        const int p = j & 1;

        v2 xjv[4];
        {
            float4 tA = *(const float4*)&s_xj[p][d0];
            float4 tB = *(const float4*)&s_xj[p][d0 + 4];
            xjv[0] = (v2){tA.x, tA.y}; xjv[1] = (v2){tA.z, tA.w};
            xjv[2] = (v2){tB.x, tB.y}; xjv[3] = (v2){tB.z, tB.w};
        }

        // sim = dot(xi,Wi) + dot(xj,Wj): packed FMAs, one DPP reduce.
        v2 sv = (v2){0.0f, 0.0f};
#pragma unroll
        for (int k = 0; k < 4; ++k) sv = __builtin_elementwise_fma(xi[k],  Wi[k], sv);
#pragma unroll
        for (int k = 0; k < 4; ++k) sv = __builtin_elementwise_fma(xjv[k], Wj[k], sv);
        const float sim = row16_sum(sv.x + sv.y);
        const v2 simv = (v2){sim, sim};
        const v2 cav  = (v2){ca, ca};
        const v2 onev = (v2){1.0f, 1.0f};
        const v2 leak = (v2){0.01f, 0.01f};

#pragma unroll
        for (int k = 0; k < 4; ++k) {
            // u = ca * (xi + sim*xj) = -2*a1*log2e * T
            v2 T2 = __builtin_elementwise_fma(simv, xjv[k], xi[k]);
            v2 u  = cav * T2;
            v2 e1 = (v2){__builtin_amdgcn_exp2f(u.x), __builtin_amdgcn_exp2f(u.y)};
            v2 d1 = e1 + onev;
            v2 r1 = (v2){__builtin_amdgcn_rcpf(d1.x), __builtin_amdgcn_rcpf(d1.y)}; // inf-safe
            v2 tnS = __builtin_elementwise_fma(G1S[k], r1, B1S[k]);  // S*(g1*tanh+b1)
            v2 alt = tnS * leak;
            v2 FvS = selMin ? __builtin_elementwise_min(tnS, alt)
                            : __builtin_elementwise_max(tnS, alt);
            za[k] += FvS;                                            // za = S * xa
            v2 e2 = (v2){__builtin_amdgcn_exp2f(za[k].x), __builtin_amdgcn_exp2f(za[k].y)};
            v2 d2 = e2 + onev;
            v2 r2 = (v2){__builtin_amdgcn_rcpf(d2.x), __builtin_amdgcn_rcpf(d2.y)};
            xi[k] = __builtin_elementwise_fma(G2[k], r2, xi[k] + B2[k]); // xi += g2*tanh+b2
        }

        // Next step's broadcaster writes the OTHER buffer; the single
        // barrier orders both visibility and WAR reuse.
        if (j + 1 < GROUP_ && row == j + 1) {
            *(v2*)&s_xj[p ^ 1][d0]     = xi[0];
            *(v2*)&s_xj[p ^ 1][d0 + 2] = xi[1];
            *(v2*)&s_xj[p ^ 1][d0 + 4] = xi[2];
            *(v2*)&s_xj[p ^ 1][d0 + 6] = xi[3];
        }
        __syncthreads();
    }

    // Recover xa = za / S
    const float invS = 1.0f / S;
    const v2 invSv = (v2){invS, invS};
    v2 xa[4];
#pragma unroll
    for (int k = 0; k < 4; ++k) xa[k] = za[k] * invSv;

    const bool valid = (g * GROUP_) < ctxlens[b];
    if (!valid) {
#pragma unroll
        for (int k = 0; k < 4; ++k) { xi[k] = (v2){0,0}; xa[k] = (v2){0,0}; }
    }

    // Scatter back through the permutation (bijective -> every out elem written)
    float* o1 = out + ((size_t)(b * L_ + tok)) * D_ + d0;
    float* o2 = o1 + (size_t)B_ * L_ * D_;
    float4 s1A = {xi[0].x, xi[0].y, xi[1].x, xi[1].y};
    float4 s1B = {xi[2].x, xi[2].y, xi[3].x, xi[3].y};
    float4 s2A = {xa[0].x, xa[0].y, xa[1].x, xa[1].y};
    float4 s2B = {xa[2].x, xa[2].y, xa[3].x, xa[3].y};
    *(float4*)o1       = s1A;
    *(float4*)(o1 + 4) = s1B;
    *(float4*)o2       = s2A;
    *(float4*)(o2 + 4) = s2B;
}

extern "C" void kernel_launch(void* const* d_in, const int* in_sizes, int n_in,
                              void* d_out, int out_size, void* d_ws, size_t ws_size,
                              hipStream_t stream) {
    const float* x  = (const float*)d_in[0];
    const int*   gt = (const int*)d_in[1];
    const int*   cl = (const int*)d_in[2];
    const float* W  = (const float*)d_in[3];
    const float* na = (const float*)d_in[4];
    const float* ng = (const float*)d_in[5];
    const float* nb = (const float*)d_in[6];
    float* out = (float*)d_out;

    ncn_kernel<<<B_ * NG_, 256, 0, stream>>>(x, gt, cl, W, na, ng, nb, out);
}